// Round 15
// baseline (339.118 us; speedup 1.0000x reference)
//
#include <hip/hip_runtime.h>
#include <hip/hip_bf16.h>
#include <math.h>

#define BB 4
#define LL 4096
#define DM 256
#define DI 512
#define DS 16
#define NOUTK 128
#define LN_EPS 1e-5f
#define NC 256
#define CLEN (LL/NC)
#define BL (BB*LL)
#define LDB 640

typedef __attribute__((ext_vector_type(8))) short short8;
typedef __attribute__((ext_vector_type(8))) ushort ushort8;
typedef __attribute__((ext_vector_type(4))) float f32x4;

__device__ __forceinline__ ushort f2bf(float f) {
    union { float f; unsigned u; } v; v.f = f;
    unsigned r = (v.u + 0x7FFF + ((v.u >> 16) & 1)) >> 16;
    return (ushort)r;
}
__device__ __forceinline__ float bf2f(ushort u) {
    union { unsigned u; float f; } v; v.u = ((unsigned)u) << 16;
    return v.f;
}

// ---------------- fused weight prep + encoder ------------------------------
// comb: rows [0,512) = dtw @ xpw[:16] (fused dtproj); [512,544) = B,C rows;
//       [544,640) = 0.
#define PREP_N1 (2*1024*256)
#define PREP_N2 (2*256*512)
#define PREP_N3 (2*640*512)
#define PREP_BLOCKS ((PREP_N1 + PREP_N2 + PREP_N3) / 256)
#define ENC_BLOCKS (BL / 4)
__global__ __launch_bounds__(256) void prep_enc_kernel(
    const float* __restrict__ inw, const float* __restrict__ opw,
    const float* __restrict__ xpw, const float* __restrict__ dtw,
    ushort* __restrict__ inw_bf, ushort* __restrict__ opw_bf,
    ushort* __restrict__ comb_bf,
    const float* __restrict__ x, const float* __restrict__ encw,
    const float* __restrict__ encb, ushort* __restrict__ hbf)
{
    int tid = threadIdx.x;
    if (blockIdx.x < PREP_BLOCKS) {
        int i = blockIdx.x * 256 + tid;
        if (i < PREP_N1) {
            inw_bf[i] = f2bf(inw[i]);
            return;
        }
        int j = i - PREP_N1;
        if (j < PREP_N2) {
            opw_bf[j] = f2bf(opw[j]);
            return;
        }
        int m = j - PREP_N2;
        if (m >= PREP_N3) return;
        int l = m / (640 * 512);
        int rem = m - l * 640 * 512;
        int row = rem >> 9, k = rem & 511;
        const float* xp = xpw + l * 48 * 512;
        const float* dw = dtw + l * 512 * 16;
        float v;
        if (row < 512) {
            v = 0.f;
            #pragma unroll
            for (int r = 0; r < 16; ++r)
                v = fmaf(dw[row * 16 + r], xp[r * 512 + k], v);
        } else if (row < 544) {
            v = xp[(row - 512 + 16) * 512 + k];
        } else v = 0.f;
        comb_bf[m] = f2bf(v);
        return;
    }
    // ---- encoder branch ----
    __shared__ float sw[256 * 33];
    __shared__ float sx[4][32];
    for (int i = tid; i < 256 * 8; i += 256) {
        float4 v = ((const float4*)encw)[i];
        int r = i >> 3, c = (i & 7) * 4;
        sw[r * 33 + c + 0] = v.x; sw[r * 33 + c + 1] = v.y;
        sw[r * 33 + c + 2] = v.z; sw[r * 33 + c + 3] = v.w;
    }
    int row0 = (blockIdx.x - PREP_BLOCKS) * 4;
    if (tid < 32) {
        for (int rr = 0; rr < 4; ++rr)
            sx[rr][tid] = x[(size_t)(row0 + rr) * 32 + tid];
    }
    __syncthreads();
    float bb = encb[tid];
    #pragma unroll
    for (int rr = 0; rr < 4; ++rr) {
        float acc = bb;
        #pragma unroll
        for (int k = 0; k < 32; ++k)
            acc = fmaf(sx[rr][k], sw[tid * 33 + k], acc);
        hbf[(size_t)(row0 + rr) * DM + tid] = f2bf(acc);
    }
}

// ---------------- bf16 MFMA GEMM: C = epi(A @ W^T) -------------------------
// Tile 64(M) x 128(N), 4 waves of 32x64, single-buffered 24 KB LDS
// (m97-style 2-barrier k-loop; latency hidden by co-resident blocks).
// FINAL CONFIG — bracketing complete over 14 rounds:
//  M {128 LOSS, 64 WIN, 32 LOSS}; N {128 WIN, 256 neutral};
//  dbuf LOSS; forced-occupancy LOSS (spill); LDS-free 2x LOSS (LDS staging
//  IS the coalescing transform); rank-16 factorization net LOSS.
// EPI: 0 plain bf16 out; 1 combined-xproj (dt softplus->bf16, B/C->f32 bc);
//      2 residual bf16 read-modify-write on Cbf.
template<int EPI, int NT>
__global__ __launch_bounds__(256, 4) void mfma_gemm(
    const ushort* __restrict__ A, int lda,
    const ushort* __restrict__ W,
    const float* __restrict__ bias,
    float* __restrict__ C, int ldc,
    ushort* Cbf, int ldcbf,
    int K)
{
    constexpr int NW = NT / 32;          // bfr count
    __shared__ ushort As[64 * 64];
    __shared__ ushort Ws[NT * 64];
    const int tid = threadIdx.x;

    // XCD-aware bijective swizzle (nwg % 8 == 0 for all our launches)
    int nwg = gridDim.x * gridDim.y;
    int wlin = blockIdx.y * gridDim.x + blockIdx.x;
    int gx = blockIdx.x, gy = blockIdx.y;
    if ((nwg & 7) == 0) {
        int q = nwg >> 3;
        int s = (wlin & 7) * q + (wlin >> 3);
        gx = s % gridDim.x;
        gy = s / gridDim.x;
    }
    const int bm = gy * 64;
    const int bn = gx * NT;
    const int wid = tid >> 6, lane = tid & 63;
    const int wrow = (wid >> 1) * 32, wcol = (wid & 1) * (NT / 2);
    const int sr = tid >> 3;
    const int sc = tid & 7;

    f32x4 acc[2][NW];
    #pragma unroll
    for (int mi = 0; mi < 2; ++mi)
        #pragma unroll
        for (int ni = 0; ni < NW; ++ni)
            acc[mi][ni] = (f32x4){0.f, 0.f, 0.f, 0.f};

    const int nk = K >> 6;          // 4 (K=256) or 8 (K=512)
    for (int t = 0; t < nk; ++t) {
        const int k0 = t << 6;
        #pragma unroll
        for (int it = 0; it < 2; ++it) {
            int r = it * 32 + sr;
            int csrc = sc ^ (r & 7);
            __builtin_amdgcn_global_load_lds(
                (const __attribute__((address_space(1))) unsigned int*)
                    (A + (size_t)(bm + r) * lda + k0 + csrc * 8),
                (__attribute__((address_space(3))) unsigned int*)
                    (As + r * 64 + sc * 8), 16, 0, 0);
        }
        #pragma unroll
        for (int it = 0; it < NW; ++it) {
            int r = it * 32 + sr;
            int csrc = sc ^ (r & 7);
            __builtin_amdgcn_global_load_lds(
                (const __attribute__((address_space(1))) unsigned int*)
                    (W + (size_t)(bn + r) * K + k0 + csrc * 8),
                (__attribute__((address_space(3))) unsigned int*)
                    (Ws + r * 64 + sc * 8), 16, 0, 0);
        }
        __syncthreads();
        #pragma unroll
        for (int kk = 0; kk < 2; ++kk) {
            short8 af[2], bfr[NW];
            #pragma unroll
            for (int mi = 0; mi < 2; ++mi) {
                int r = wrow + mi * 16 + (lane & 15);
                int c = (lane >> 4) + kk * 4;
                af[mi] = *(const short8*)(As + r * 64 + ((c ^ (r & 7)) << 3));
            }
            #pragma unroll
            for (int ni = 0; ni < NW; ++ni) {
                int r = wcol + ni * 16 + (lane & 15);
                int c = (lane >> 4) + kk * 4;
                bfr[ni] = *(const short8*)(Ws + r * 64 + ((c ^ (r & 7)) << 3));
            }
            #pragma unroll
            for (int mi = 0; mi < 2; ++mi)
                #pragma unroll
                for (int ni = 0; ni < NW; ++ni)
                    acc[mi][ni] = __builtin_amdgcn_mfma_f32_16x16x32_bf16(
                        af[mi], bfr[ni], acc[mi][ni], 0, 0, 0);
        }
        __syncthreads();
    }

    #pragma unroll
    for (int mi = 0; mi < 2; ++mi)
        #pragma unroll
        for (int ni = 0; ni < NW; ++ni) {
            int col = bn + wcol + ni * 16 + (lane & 15);
            #pragma unroll
            for (int r = 0; r < 4; ++r) {
                int row = bm + wrow + mi * 16 + (lane >> 4) * 4 + r;
                float v = acc[mi][ni][r];
                if (EPI == 1) {
                    if (col < 512) {
                        float u = v + bias[col];
                        float sp = fmaxf(u, 0.f) + __logf(1.f + __expf(-fabsf(u)));
                        Cbf[(size_t)row * ldcbf + col] = f2bf(sp);
                    } else if (col < 544) {
                        C[(size_t)row * ldc + (col - 512)] = v;
                    }
                } else if (EPI == 2) {
                    size_t o = (size_t)row * ldcbf + col;
                    float vv = v + bf2f(Cbf[o]);
                    Cbf[o] = f2bf(vv);
                } else {
                    Cbf[(size_t)row * ldcbf + col] = f2bf(v);
                }
            }
        }
}

// ---------------- causal conv (width 4) + bias + silu, bf16 in/out ---------
// 16B/lane (ushort8): each thread walks 8 timesteps for 8 channels.
__global__ __launch_bounds__(256) void conv_silu_kernel(
    const ushort* __restrict__ xz, const float* __restrict__ cw,
    const float* __restrict__ cb, ushort* __restrict__ xi)
{
    int idx = blockIdx.x * 256 + threadIdx.x;   // over (BL/8)*64
    int d8 = (idx & 63) * 8;
    int grp = idx >> 6;                          // 0 .. BL/8-1
    int b = grp >> 9;                            // LL/8 = 512 groups per b
    int t0 = (grp & 511) * 8;
    const ushort* base = xz + ((size_t)(b * LL + t0) * 1024) + d8;
    ushort* obase = xi + ((size_t)(b * LL + t0) * 512) + d8;

    float wv[8][4];
    float bv[8];
    #pragma unroll
    for (int j = 0; j < 8; ++j) {
        float4 w = *(const float4*)(cw + (d8 + j) * 4);
        wv[j][0] = w.x; wv[j][1] = w.y; wv[j][2] = w.z; wv[j][3] = w.w;
        bv[j] = cb[d8 + j];
    }

    ushort8 z8 = {0,0,0,0,0,0,0,0};
    ushort8 win0 = (t0 >= 3) ? *(const ushort8*)(base - 3 * 1024) : z8;
    ushort8 win1 = (t0 >= 2) ? *(const ushort8*)(base - 2 * 1024) : z8;
    ushort8 win2 = (t0 >= 1) ? *(const ushort8*)(base - 1 * 1024) : z8;

    #pragma unroll
    for (int k = 0; k < 8; ++k) {
        ushort8 cur = *(const ushort8*)(base + k * 1024);
        ushort8 o;
        #pragma unroll
        for (int j = 0; j < 8; ++j) {
            float a = bv[j];
            a = fmaf(bf2f(win0[j]), wv[j][0], a);
            a = fmaf(bf2f(win1[j]), wv[j][1], a);
            a = fmaf(bf2f(win2[j]), wv[j][2], a);
            a = fmaf(bf2f(cur[j]),  wv[j][3], a);
            o[j] = f2bf(a / (1.f + __expf(-a)));
        }
        *(ushort8*)(obase + k * 512) = o;
        win0 = win1; win1 = win2; win2 = cur;
    }
}

// ---------------- chunked selective scan -----------------------------------
// R15: NC 128 -> 256 (CLEN 32 -> 16): halves the serial per-block chain in
// phase1/phase3 and doubles block count (1024 -> 2048 = 8/CU) — the same
// latency-hiding parameter class that won in R2 and the conv rewrite.
__global__ __launch_bounds__(256) void scan_phase1(
    const ushort* __restrict__ xi, const ushort* __restrict__ dtb,
    const float* __restrict__ bc,
    const float* __restrict__ alog,
    float* __restrict__ cS, float* __restrict__ cH)
{
    int d = blockIdx.z * 256 + threadIdx.x;
    int b = blockIdx.y, c = blockIdx.x;
    float Av[16];
    bool fast = true;
    #pragma unroll
    for (int s = 0; s < 16; ++s) {
        Av[s] = -__expf(alog[d * 16 + s]);
        fast = fast && (fabsf(Av[s] + (float)(s + 1)) < 1e-3f * (s + 1));
    }
    float h[16];
    #pragma unroll
    for (int s = 0; s < 16; ++s) h[s] = 0.f;
    float S = 0.f;
    int t0 = c * CLEN;
    if (fast) {
        for (int t = t0; t < t0 + CLEN; ++t) {
            size_t row = (size_t)b * LL + t;
            float dt = bf2f(dtb[row * 512 + d]);
            float x = bf2f(xi[row * 512 + d]);
            float dtx = dt * x;
            S += dt;
            const float* bp = bc + row * 32;
            float e1 = __expf(-dt);
            float e2=e1*e1, e3=e2*e1, e4=e2*e2, e5=e3*e2, e6=e3*e3, e7=e4*e3, e8=e4*e4;
            float e9=e5*e4, e10=e5*e5, e11=e6*e5, e12=e6*e6, e13=e7*e6, e14=e7*e7, e15=e8*e7, e16=e8*e8;
            float pw[16] = {e1,e2,e3,e4,e5,e6,e7,e8,e9,e10,e11,e12,e13,e14,e15,e16};
            #pragma unroll
            for (int s = 0; s < 16; ++s)
                h[s] = fmaf(pw[s], h[s], dtx * bp[s]);
        }
    } else {
        for (int t = t0; t < t0 + CLEN; ++t) {
            size_t row = (size_t)b * LL + t;
            float dt = bf2f(dtb[row * 512 + d]);
            float x = bf2f(xi[row * 512 + d]);
            float dtx = dt * x;
            S += dt;
            const float* bp = bc + row * 32;
            #pragma unroll
            for (int s = 0; s < 16; ++s) {
                float dA = __expf(dt * Av[s]);
                h[s] = fmaf(dA, h[s], dtx * bp[s]);
            }
        }
    }
    cS[((size_t)b * DI + d) * NC + c] = S;
    size_t base = (((size_t)b * DI + d) * NC + c) * 16;
    #pragma unroll
    for (int q = 0; q < 4; ++q)
        *(float4*)(cH + base + q*4) = *(float4*)&h[q*4];
}

// Parallel chunk-prefix: one block per (b,d); 16 threads per s-value,
// each composing NC/16 = 16 chunks; shfl-scan of affine maps F(x)=Ax+H
// across the 16-lane segment (serial chain 256 -> 16+4+16).
__global__ __launch_bounds__(256) void scan_phase2(
    const float* __restrict__ cS, float* __restrict__ cH,
    const float* __restrict__ alog)
{
    int bd = blockIdx.x;            // b*DI + d
    int d = bd & (DI - 1);
    int tid = threadIdx.x;
    int s = tid >> 4;               // 0..15
    int g = tid & 15;               // chunk group (16 chunks each)
    float Avs = -__expf(alog[d * 16 + s]);
    size_t sbase = (size_t)bd * NC;
    size_t base = (size_t)bd * NC * 16 + s;
    float a16[16], h16[16];
    #pragma unroll
    for (int j = 0; j < 16; ++j) {
        float Sj = cS[sbase + g * 16 + j];
        a16[j] = __expf(Avs * Sj);
        h16[j] = cH[base + (size_t)(g * 16 + j) * 16];
    }
    float A = 1.f, H = 0.f;
    #pragma unroll
    for (int j = 0; j < 16; ++j) {
        H = fmaf(a16[j], H, h16[j]);
        A *= a16[j];
    }
    #pragma unroll
    for (int off = 1; off < 16; off <<= 1) {
        float Ap = __shfl_up(A, off, 16);
        float Hp = __shfl_up(H, off, 16);
        if (g >= off) { H = fmaf(A, Hp, H); A *= Ap; }
    }
    float init = __shfl_up(H, 1, 16);
    if (g == 0) init = 0.f;
    #pragma unroll
    for (int j = 0; j < 16; ++j) {
        size_t o = base + (size_t)(g * 16 + j) * 16;
        cH[o] = init;
        init = fmaf(a16[j], init, h16[j]);
    }
}

__global__ __launch_bounds__(256) void scan_phase3(
    const ushort* __restrict__ xz,   // bf16, ld 1024; res at cols 512..1023
    ushort* __restrict__ xi,
    const ushort* __restrict__ dtb,
    const float* __restrict__ bc,
    const float* __restrict__ alog,
    const float* __restrict__ Dp,
    const float* __restrict__ cH,
    int c0)
{
    int d = blockIdx.z * 256 + threadIdx.x;
    int b = blockIdx.y;
    int c = blockIdx.x + c0;
    float Av[16];
    bool fast = true;
    #pragma unroll
    for (int s = 0; s < 16; ++s) {
        Av[s] = -__expf(alog[d * 16 + s]);
        fast = fast && (fabsf(Av[s] + (float)(s + 1)) < 1e-3f * (s + 1));
    }
    float h[16];
    size_t cbase = (((size_t)b * DI + d) * NC + c) * 16;
    #pragma unroll
    for (int q = 0; q < 4; ++q)
        *(float4*)&h[q*4] = *(const float4*)(cH + cbase + q*4);
    float Dd = Dp[d];
    int t0 = c * CLEN;
    if (fast) {
        for (int t = t0; t < t0 + CLEN; ++t) {
            size_t row = (size_t)b * LL + t;
            float dt = bf2f(dtb[row * 512 + d]);
            float x = bf2f(xi[row * 512 + d]);
            float dtx = dt * x;
            const float* bp = bc + row * 32;
            const float* cp = bc + row * 32 + 16;
            float e1 = __expf(-dt);
            float e2=e1*e1, e3=e2*e1, e4=e2*e2, e5=e3*e2, e6=e3*e3, e7=e4*e3, e8=e4*e4;
            float e9=e5*e4, e10=e5*e5, e11=e6*e5, e12=e6*e6, e13=e7*e6, e14=e7*e7, e15=e8*e7, e16=e8*e8;
            float pw[16] = {e1,e2,e3,e4,e5,e6,e7,e8,e9,e10,e11,e12,e13,e14,e15,e16};
            float y = 0.f;
            #pragma unroll
            for (int s = 0; s < 16; ++s) {
                h[s] = fmaf(pw[s], h[s], dtx * bp[s]);
                y = fmaf(h[s], cp[s], y);
            }
            float res = bf2f(xz[row * 1024 + 512 + d]);
            float g = (y + x * Dd) * (res / (1.f + __expf(-res)));
            xi[row * 512 + d] = f2bf(g);
        }
    } else {
        for (int t = t0; t < t0 + CLEN; ++t) {
            size_t row = (size_t)b * LL + t;
            float dt = bf2f(dtb[row * 512 + d]);
            float x = bf2f(xi[row * 512 + d]);
            float dtx = dt * x;
            const float* bp = bc + row * 32;
            const float* cp = bc + row * 32 + 16;
            float y = 0.f;
            #pragma unroll
            for (int s = 0; s < 16; ++s) {
                float dA = __expf(dt * Av[s]);
                h[s] = fmaf(dA, h[s], dtx * bp[s]);
                y = fmaf(h[s], cp[s], y);
            }
            float res = bf2f(xz[row * 1024 + 512 + d]);
            float g = (y + x * Dd) * (res / (1.f + __expf(-res)));
            xi[row * 512 + d] = f2bf(g);
        }
    }
}

// ---------------- fused tail: out_proj(last row) + residual + LN + head ----
__global__ __launch_bounds__(256) void tail_kernel(
    const ushort* __restrict__ xi, const float* __restrict__ W,
    const ushort* __restrict__ hbf,
    const float* __restrict__ lng, const float* __restrict__ lnb,
    const float* __restrict__ hw, const float* __restrict__ hb,
    float* __restrict__ out)
{
    int b = blockIdx.x, tid = threadIdx.x;
    __shared__ float sy[DI];
    __shared__ float sh[DM];
    __shared__ float r1[4], r2[4];
    const ushort* yrow = xi + ((size_t)b * LL + (LL - 1)) * DI;
    for (int k = tid; k < DI; k += 256) sy[k] = bf2f(yrow[k]);
    __syncthreads();
    const float* wr = W + (size_t)tid * DI;
    float acc = 0.f;
    for (int k = 0; k < DI; k += 4) {
        float4 wv = *(const float4*)(wr + k);
        acc = fmaf(sy[k+0], wv.x, acc);
        acc = fmaf(sy[k+1], wv.y, acc);
        acc = fmaf(sy[k+2], wv.z, acc);
        acc = fmaf(sy[k+3], wv.w, acc);
    }
    float v = acc + bf2f(hbf[((size_t)b * LL + (LL - 1)) * DM + tid]);

    float s = v;
    #pragma unroll
    for (int o = 32; o >= 1; o >>= 1) s += __shfl_down(s, o);
    if ((tid & 63) == 0) r1[tid >> 6] = s;
    __syncthreads();
    float mu = (r1[0] + r1[1] + r1[2] + r1[3]) * (1.f / 256.f);
    float dv = v - mu;
    float q = dv * dv;
    #pragma unroll
    for (int o = 32; o >= 1; o >>= 1) q += __shfl_down(q, o);
    if ((tid & 63) == 0) r2[tid >> 6] = q;
    __syncthreads();
    float var = (r2[0] + r2[1] + r2[2] + r2[3]) * (1.f / 256.f);
    sh[tid] = dv * rsqrtf(var + LN_EPS) * lng[tid] + lnb[tid];
    __syncthreads();
    if (tid < NOUTK) {
        const float* hr = hw + (size_t)tid * DM;
        float a2 = hb[tid];
        for (int d2 = 0; d2 < DM; d2 += 4) {
            float4 wv = *(const float4*)(hr + d2);
            a2 = fmaf(sh[d2+0], wv.x, a2);
            a2 = fmaf(sh[d2+1], wv.y, a2);
            a2 = fmaf(sh[d2+2], wv.z, a2);
            a2 = fmaf(sh[d2+3], wv.w, a2);
        }
        out[b * NOUTK + tid] = a2;
    }
}

extern "C" void kernel_launch(void* const* d_in, const int* in_sizes, int n_in,
                              void* d_out, int out_size, void* d_ws, size_t ws_size,
                              hipStream_t stream)
{
    const float* x    = (const float*)d_in[0];
    const float* encw = (const float*)d_in[1];
    const float* encb = (const float*)d_in[2];
    const float* inw  = (const float*)d_in[3];
    const float* cw   = (const float*)d_in[4];
    const float* cb   = (const float*)d_in[5];
    const float* xpw  = (const float*)d_in[6];
    const float* dtw  = (const float*)d_in[7];
    const float* dtb  = (const float*)d_in[8];
    const float* alog = (const float*)d_in[9];
    const float* Dp   = (const float*)d_in[10];
    const float* opw  = (const float*)d_in[11];
    const float* lng  = (const float*)d_in[12];
    const float* lnb  = (const float*)d_in[13];
    const float* hw   = (const float*)d_in[14];
    const float* hb   = (const float*)d_in[15];
    float* out = (float*)d_out;

    float* ws   = (float*)d_ws;
    float* bc   = ws;                               // BL*32 f32 (B|C)
    float* cS   = bc  + (size_t)BL * 32;            // B*DI*NC f32 (sum dt)
    float* cH   = cS  + (size_t)BB * DI * NC;       // B*DI*NC*16 f32
    ushort* h_bf    = (ushort*)(cH + (size_t)BB * DI * NC * DS);  // BL*256
    ushort* xz_bf   = h_bf  + (size_t)BL * DM;      // BL*1024
    ushort* xi_bf   = xz_bf + (size_t)BL * 1024;    // BL*512
    ushort* dt_bf   = xi_bf + (size_t)BL * DI;      // BL*512 (softplus'd dt)
    ushort* inw_bf  = dt_bf + (size_t)BL * DI;      // 2*1024*256
    ushort* opw_bf  = inw_bf + 2 * 1024 * DM;       // 2*256*512
    ushort* comb_bf = opw_bf + 2 * DM * DI;         // 2*640*512

    dim3 blk(256, 1, 1);

    prep_enc_kernel<<<dim3(PREP_BLOCKS + ENC_BLOCKS), blk, 0, stream>>>(
        inw, opw, xpw, dtw, inw_bf, opw_bf, comb_bf,
        x, encw, encb, h_bf);

    for (int l = 0; l < 2; ++l) {
        // in_proj -> xz_bf (bf16 only) — proven NT=128
        mfma_gemm<0, 128><<<dim3(1024/128, BL/64), blk, 0, stream>>>(
            h_bf, DM, inw_bf + (size_t)l * 1024 * DM, nullptr,
            nullptr, 0, xz_bf, 1024, DM);
        // conv + silu -> xi_bf
        conv_silu_kernel<<<dim3(BL * 64 / 8 / 256), blk, 0, stream>>>(
            xz_bf, cw + l * DI * 4, cb + l * DI, xi_bf);
        // combined xproj+dtproj: dt_bf = bf16(softplus(xi@Wdt^T + dtb)),
        // bc = f32 [B|C]
        mfma_gemm<1, 128><<<dim3(LDB/128, BL/64), blk, 0, stream>>>(
            xi_bf, DI, comb_bf + (size_t)l * LDB * DI, dtb + l * DI,
            bc, 32, dt_bf, 512, DI);
        // scan (NC=256, CLEN=16)
        scan_phase1<<<dim3(NC, BB, 2), blk, 0, stream>>>(
            xi_bf, dt_bf, bc, alog + (size_t)l * DI * 16, cS, cH);
        scan_phase2<<<dim3(BB * DI), blk, 0, stream>>>(
            cS, cH, alog + (size_t)l * DI * 16);
        if (l == 0) {
            scan_phase3<<<dim3(NC, BB, 2), blk, 0, stream>>>(
                xz_bf, xi_bf, dt_bf, bc, alog + (size_t)l * DI * 16,
                Dp + l * DI, cH, 0);
            // out_proj with bf16 residual read-modify-write on h_bf
            mfma_gemm<2, 128><<<dim3(DM/128, BL/64), blk, 0, stream>>>(
                xi_bf, DI, opw_bf + (size_t)l * DM * DI, nullptr,
                nullptr, 0, h_bf, DM, DI);
        } else {
            scan_phase3<<<dim3(1, BB, 2), blk, 0, stream>>>(
                xz_bf, xi_bf, dt_bf, bc, alog + (size_t)l * DI * 16,
                Dp + l * DI, cH, NC - 1);
            tail_kernel<<<dim3(BB), blk, 0, stream>>>(
                xi_bf, opw + (size_t)l * DM * DI, h_bf,
                lng, lnb, hw, hb, out);
        }
    }
}

// Round 16
// 304.068 us; speedup vs baseline: 1.1153x; 1.1153x over previous
//
#include <hip/hip_runtime.h>
#include <hip/hip_bf16.h>
#include <math.h>

#define BB 4
#define LL 4096
#define DM 256
#define DI 512
#define DS 16
#define NOUTK 128
#define LN_EPS 1e-5f
#define NC 128
#define CLEN (LL/NC)
#define BL (BB*LL)
#define LDB 640

typedef __attribute__((ext_vector_type(8))) short short8;
typedef __attribute__((ext_vector_type(8))) ushort ushort8;
typedef __attribute__((ext_vector_type(4))) float f32x4;

__device__ __forceinline__ ushort f2bf(float f) {
    union { float f; unsigned u; } v; v.f = f;
    unsigned r = (v.u + 0x7FFF + ((v.u >> 16) & 1)) >> 16;
    return (ushort)r;
}
__device__ __forceinline__ float bf2f(ushort u) {
    union { unsigned u; float f; } v; v.u = ((unsigned)u) << 16;
    return v.f;
}

// ---------------- fused weight prep + encoder ------------------------------
// comb: rows [0,512) = dtw @ xpw[:16] (fused dtproj); [512,544) = B,C rows;
//       [544,640) = 0.
#define PREP_N1 (2*1024*256)
#define PREP_N2 (2*256*512)
#define PREP_N3 (2*640*512)
#define PREP_BLOCKS ((PREP_N1 + PREP_N2 + PREP_N3) / 256)
#define ENC_BLOCKS (BL / 4)
__global__ __launch_bounds__(256) void prep_enc_kernel(
    const float* __restrict__ inw, const float* __restrict__ opw,
    const float* __restrict__ xpw, const float* __restrict__ dtw,
    ushort* __restrict__ inw_bf, ushort* __restrict__ opw_bf,
    ushort* __restrict__ comb_bf,
    const float* __restrict__ x, const float* __restrict__ encw,
    const float* __restrict__ encb, ushort* __restrict__ hbf)
{
    int tid = threadIdx.x;
    if (blockIdx.x < PREP_BLOCKS) {
        int i = blockIdx.x * 256 + tid;
        if (i < PREP_N1) {
            inw_bf[i] = f2bf(inw[i]);
            return;
        }
        int j = i - PREP_N1;
        if (j < PREP_N2) {
            opw_bf[j] = f2bf(opw[j]);
            return;
        }
        int m = j - PREP_N2;
        if (m >= PREP_N3) return;
        int l = m / (640 * 512);
        int rem = m - l * 640 * 512;
        int row = rem >> 9, k = rem & 511;
        const float* xp = xpw + l * 48 * 512;
        const float* dw = dtw + l * 512 * 16;
        float v;
        if (row < 512) {
            v = 0.f;
            #pragma unroll
            for (int r = 0; r < 16; ++r)
                v = fmaf(dw[row * 16 + r], xp[r * 512 + k], v);
        } else if (row < 544) {
            v = xp[(row - 512 + 16) * 512 + k];
        } else v = 0.f;
        comb_bf[m] = f2bf(v);
        return;
    }
    // ---- encoder branch ----
    __shared__ float sw[256 * 33];
    __shared__ float sx[4][32];
    for (int i = tid; i < 256 * 8; i += 256) {
        float4 v = ((const float4*)encw)[i];
        int r = i >> 3, c = (i & 7) * 4;
        sw[r * 33 + c + 0] = v.x; sw[r * 33 + c + 1] = v.y;
        sw[r * 33 + c + 2] = v.z; sw[r * 33 + c + 3] = v.w;
    }
    int row0 = (blockIdx.x - PREP_BLOCKS) * 4;
    if (tid < 32) {
        for (int rr = 0; rr < 4; ++rr)
            sx[rr][tid] = x[(size_t)(row0 + rr) * 32 + tid];
    }
    __syncthreads();
    float bb = encb[tid];
    #pragma unroll
    for (int rr = 0; rr < 4; ++rr) {
        float acc = bb;
        #pragma unroll
        for (int k = 0; k < 32; ++k)
            acc = fmaf(sx[rr][k], sw[tid * 33 + k], acc);
        hbf[(size_t)(row0 + rr) * DM + tid] = f2bf(acc);
    }
}

// ---------------- bf16 MFMA GEMM: C = epi(A @ W^T) -------------------------
// Tile 64(M) x 128(N), 4 waves of 32x64, single-buffered 24 KB LDS
// (m97-style 2-barrier k-loop; latency hidden by co-resident blocks).
// FINAL CONFIG — bracketing complete over 15 rounds:
//  M {128 LOSS, 64 WIN, 32 LOSS}; N {128 WIN, 256 neutral};
//  dbuf LOSS; forced-occupancy LOSS (spill); LDS-free 2x LOSS (LDS staging
//  IS the coalescing transform); rank-16 factorization net LOSS;
//  scan NC {128 WIN, 256 LOSS}.
// EPI: 0 plain bf16 out; 1 combined-xproj (dt softplus->bf16, B/C->f32 bc);
//      2 residual bf16 read-modify-write on Cbf.
template<int EPI>
__global__ __launch_bounds__(256, 4) void mfma_gemm(
    const ushort* __restrict__ A, int lda,
    const ushort* __restrict__ W,
    const float* __restrict__ bias,
    float* __restrict__ C, int ldc,
    ushort* Cbf, int ldcbf,
    int K)
{
    __shared__ ushort As[64 * 64];
    __shared__ ushort Ws[128 * 64];
    const int tid = threadIdx.x;

    // XCD-aware bijective swizzle (nwg % 8 == 0 for all our launches)
    int nwg = gridDim.x * gridDim.y;
    int wlin = blockIdx.y * gridDim.x + blockIdx.x;
    int gx = blockIdx.x, gy = blockIdx.y;
    if ((nwg & 7) == 0) {
        int q = nwg >> 3;
        int s = (wlin & 7) * q + (wlin >> 3);
        gx = s % gridDim.x;
        gy = s / gridDim.x;
    }
    const int bm = gy * 64;
    const int bn = gx * 128;
    const int wid = tid >> 6, lane = tid & 63;
    const int wrow = (wid >> 1) * 32, wcol = (wid & 1) * 64;
    const int sr = tid >> 3;
    const int sc = tid & 7;

    f32x4 acc[2][4];
    #pragma unroll
    for (int mi = 0; mi < 2; ++mi)
        #pragma unroll
        for (int ni = 0; ni < 4; ++ni)
            acc[mi][ni] = (f32x4){0.f, 0.f, 0.f, 0.f};

    const int nk = K >> 6;          // 4 (K=256) or 8 (K=512)
    for (int t = 0; t < nk; ++t) {
        const int k0 = t << 6;
        #pragma unroll
        for (int it = 0; it < 2; ++it) {
            int r = it * 32 + sr;
            int csrc = sc ^ (r & 7);
            __builtin_amdgcn_global_load_lds(
                (const __attribute__((address_space(1))) unsigned int*)
                    (A + (size_t)(bm + r) * lda + k0 + csrc * 8),
                (__attribute__((address_space(3))) unsigned int*)
                    (As + r * 64 + sc * 8), 16, 0, 0);
        }
        #pragma unroll
        for (int it = 0; it < 4; ++it) {
            int r = it * 32 + sr;
            int csrc = sc ^ (r & 7);
            __builtin_amdgcn_global_load_lds(
                (const __attribute__((address_space(1))) unsigned int*)
                    (W + (size_t)(bn + r) * K + k0 + csrc * 8),
                (__attribute__((address_space(3))) unsigned int*)
                    (Ws + r * 64 + sc * 8), 16, 0, 0);
        }
        __syncthreads();
        #pragma unroll
        for (int kk = 0; kk < 2; ++kk) {
            short8 af[2], bfr[4];
            #pragma unroll
            for (int mi = 0; mi < 2; ++mi) {
                int r = wrow + mi * 16 + (lane & 15);
                int c = (lane >> 4) + kk * 4;
                af[mi] = *(const short8*)(As + r * 64 + ((c ^ (r & 7)) << 3));
            }
            #pragma unroll
            for (int ni = 0; ni < 4; ++ni) {
                int r = wcol + ni * 16 + (lane & 15);
                int c = (lane >> 4) + kk * 4;
                bfr[ni] = *(const short8*)(Ws + r * 64 + ((c ^ (r & 7)) << 3));
            }
            #pragma unroll
            for (int mi = 0; mi < 2; ++mi)
                #pragma unroll
                for (int ni = 0; ni < 4; ++ni)
                    acc[mi][ni] = __builtin_amdgcn_mfma_f32_16x16x32_bf16(
                        af[mi], bfr[ni], acc[mi][ni], 0, 0, 0);
        }
        __syncthreads();
    }

    #pragma unroll
    for (int mi = 0; mi < 2; ++mi)
        #pragma unroll
        for (int ni = 0; ni < 4; ++ni) {
            int col = bn + wcol + ni * 16 + (lane & 15);
            #pragma unroll
            for (int r = 0; r < 4; ++r) {
                int row = bm + wrow + mi * 16 + (lane >> 4) * 4 + r;
                float v = acc[mi][ni][r];
                if (EPI == 1) {
                    if (col < 512) {
                        float u = v + bias[col];
                        float sp = fmaxf(u, 0.f) + __logf(1.f + __expf(-fabsf(u)));
                        Cbf[(size_t)row * ldcbf + col] = f2bf(sp);
                    } else if (col < 544) {
                        C[(size_t)row * ldc + (col - 512)] = v;
                    }
                } else if (EPI == 2) {
                    size_t o = (size_t)row * ldcbf + col;
                    float vv = v + bf2f(Cbf[o]);
                    Cbf[o] = f2bf(vv);
                } else {
                    Cbf[(size_t)row * ldcbf + col] = f2bf(v);
                }
            }
        }
}

// ---------------- causal conv (width 4) + bias + silu, bf16 in/out ---------
// 16B/lane (ushort8): each thread walks 8 timesteps for 8 channels.
__global__ __launch_bounds__(256) void conv_silu_kernel(
    const ushort* __restrict__ xz, const float* __restrict__ cw,
    const float* __restrict__ cb, ushort* __restrict__ xi)
{
    int idx = blockIdx.x * 256 + threadIdx.x;   // over (BL/8)*64
    int d8 = (idx & 63) * 8;
    int grp = idx >> 6;                          // 0 .. BL/8-1
    int b = grp >> 9;                            // LL/8 = 512 groups per b
    int t0 = (grp & 511) * 8;
    const ushort* base = xz + ((size_t)(b * LL + t0) * 1024) + d8;
    ushort* obase = xi + ((size_t)(b * LL + t0) * 512) + d8;

    float wv[8][4];
    float bv[8];
    #pragma unroll
    for (int j = 0; j < 8; ++j) {
        float4 w = *(const float4*)(cw + (d8 + j) * 4);
        wv[j][0] = w.x; wv[j][1] = w.y; wv[j][2] = w.z; wv[j][3] = w.w;
        bv[j] = cb[d8 + j];
    }

    ushort8 z8 = {0,0,0,0,0,0,0,0};
    ushort8 win0 = (t0 >= 3) ? *(const ushort8*)(base - 3 * 1024) : z8;
    ushort8 win1 = (t0 >= 2) ? *(const ushort8*)(base - 2 * 1024) : z8;
    ushort8 win2 = (t0 >= 1) ? *(const ushort8*)(base - 1 * 1024) : z8;

    #pragma unroll
    for (int k = 0; k < 8; ++k) {
        ushort8 cur = *(const ushort8*)(base + k * 1024);
        ushort8 o;
        #pragma unroll
        for (int j = 0; j < 8; ++j) {
            float a = bv[j];
            a = fmaf(bf2f(win0[j]), wv[j][0], a);
            a = fmaf(bf2f(win1[j]), wv[j][1], a);
            a = fmaf(bf2f(win2[j]), wv[j][2], a);
            a = fmaf(bf2f(cur[j]),  wv[j][3], a);
            o[j] = f2bf(a / (1.f + __expf(-a)));
        }
        *(ushort8*)(obase + k * 512) = o;
        win0 = win1; win1 = win2; win2 = cur;
    }
}

// ---------------- chunked selective scan -----------------------------------
__global__ __launch_bounds__(256) void scan_phase1(
    const ushort* __restrict__ xi, const ushort* __restrict__ dtb,
    const float* __restrict__ bc,
    const float* __restrict__ alog,
    float* __restrict__ cS, float* __restrict__ cH)
{
    int d = blockIdx.z * 256 + threadIdx.x;
    int b = blockIdx.y, c = blockIdx.x;
    float Av[16];
    bool fast = true;
    #pragma unroll
    for (int s = 0; s < 16; ++s) {
        Av[s] = -__expf(alog[d * 16 + s]);
        fast = fast && (fabsf(Av[s] + (float)(s + 1)) < 1e-3f * (s + 1));
    }
    float h[16];
    #pragma unroll
    for (int s = 0; s < 16; ++s) h[s] = 0.f;
    float S = 0.f;
    int t0 = c * CLEN;
    if (fast) {
        for (int t = t0; t < t0 + CLEN; ++t) {
            size_t row = (size_t)b * LL + t;
            float dt = bf2f(dtb[row * 512 + d]);
            float x = bf2f(xi[row * 512 + d]);
            float dtx = dt * x;
            S += dt;
            const float* bp = bc + row * 32;
            float e1 = __expf(-dt);
            float e2=e1*e1, e3=e2*e1, e4=e2*e2, e5=e3*e2, e6=e3*e3, e7=e4*e3, e8=e4*e4;
            float e9=e5*e4, e10=e5*e5, e11=e6*e5, e12=e6*e6, e13=e7*e6, e14=e7*e7, e15=e8*e7, e16=e8*e8;
            float pw[16] = {e1,e2,e3,e4,e5,e6,e7,e8,e9,e10,e11,e12,e13,e14,e15,e16};
            #pragma unroll
            for (int s = 0; s < 16; ++s)
                h[s] = fmaf(pw[s], h[s], dtx * bp[s]);
        }
    } else {
        for (int t = t0; t < t0 + CLEN; ++t) {
            size_t row = (size_t)b * LL + t;
            float dt = bf2f(dtb[row * 512 + d]);
            float x = bf2f(xi[row * 512 + d]);
            float dtx = dt * x;
            S += dt;
            const float* bp = bc + row * 32;
            #pragma unroll
            for (int s = 0; s < 16; ++s) {
                float dA = __expf(dt * Av[s]);
                h[s] = fmaf(dA, h[s], dtx * bp[s]);
            }
        }
    }
    cS[((size_t)b * DI + d) * NC + c] = S;
    size_t base = (((size_t)b * DI + d) * NC + c) * 16;
    #pragma unroll
    for (int q = 0; q < 4; ++q)
        *(float4*)(cH + base + q*4) = *(float4*)&h[q*4];
}

// Parallel chunk-prefix: one block per (b,d); 16 threads per s-value,
// each composing 8 chunks; shfl-scan of affine maps F(x)=Ax+H across the
// 16-lane segment (serial chain 128 -> 8+4+8). Decay a = exp(Av[s]*S).
__global__ __launch_bounds__(256) void scan_phase2(
    const float* __restrict__ cS, float* __restrict__ cH,
    const float* __restrict__ alog)
{
    int bd = blockIdx.x;            // b*DI + d
    int d = bd & (DI - 1);
    int tid = threadIdx.x;
    int s = tid >> 4;               // 0..15
    int g = tid & 15;               // chunk group (8 chunks each)
    float Avs = -__expf(alog[d * 16 + s]);
    size_t sbase = (size_t)bd * NC;
    size_t base = (size_t)bd * NC * 16 + s;
    float a8[8], h8[8];
    #pragma unroll
    for (int j = 0; j < 8; ++j) {
        float Sj = cS[sbase + g * 8 + j];
        a8[j] = __expf(Avs * Sj);
        h8[j] = cH[base + (size_t)(g * 8 + j) * 16];
    }
    float A = 1.f, H = 0.f;
    #pragma unroll
    for (int j = 0; j < 8; ++j) {
        H = fmaf(a8[j], H, h8[j]);
        A *= a8[j];
    }
    #pragma unroll
    for (int off = 1; off < 16; off <<= 1) {
        float Ap = __shfl_up(A, off, 16);
        float Hp = __shfl_up(H, off, 16);
        if (g >= off) { H = fmaf(A, Hp, H); A *= Ap; }
    }
    float init = __shfl_up(H, 1, 16);
    if (g == 0) init = 0.f;
    #pragma unroll
    for (int j = 0; j < 8; ++j) {
        size_t o = base + (size_t)(g * 8 + j) * 16;
        cH[o] = init;
        init = fmaf(a8[j], init, h8[j]);
    }
}

__global__ __launch_bounds__(256) void scan_phase3(
    const ushort* __restrict__ xz,   // bf16, ld 1024; res at cols 512..1023
    ushort* __restrict__ xi,
    const ushort* __restrict__ dtb,
    const float* __restrict__ bc,
    const float* __restrict__ alog,
    const float* __restrict__ Dp,
    const float* __restrict__ cH,
    int c0)
{
    int d = blockIdx.z * 256 + threadIdx.x;
    int b = blockIdx.y;
    int c = blockIdx.x + c0;
    float Av[16];
    bool fast = true;
    #pragma unroll
    for (int s = 0; s < 16; ++s) {
        Av[s] = -__expf(alog[d * 16 + s]);
        fast = fast && (fabsf(Av[s] + (float)(s + 1)) < 1e-3f * (s + 1));
    }
    float h[16];
    size_t cbase = (((size_t)b * DI + d) * NC + c) * 16;
    #pragma unroll
    for (int q = 0; q < 4; ++q)
        *(float4*)&h[q*4] = *(const float4*)(cH + cbase + q*4);
    float Dd = Dp[d];
    int t0 = c * CLEN;
    if (fast) {
        for (int t = t0; t < t0 + CLEN; ++t) {
            size_t row = (size_t)b * LL + t;
            float dt = bf2f(dtb[row * 512 + d]);
            float x = bf2f(xi[row * 512 + d]);
            float dtx = dt * x;
            const float* bp = bc + row * 32;
            const float* cp = bc + row * 32 + 16;
            float e1 = __expf(-dt);
            float e2=e1*e1, e3=e2*e1, e4=e2*e2, e5=e3*e2, e6=e3*e3, e7=e4*e3, e8=e4*e4;
            float e9=e5*e4, e10=e5*e5, e11=e6*e5, e12=e6*e6, e13=e7*e6, e14=e7*e7, e15=e8*e7, e16=e8*e8;
            float pw[16] = {e1,e2,e3,e4,e5,e6,e7,e8,e9,e10,e11,e12,e13,e14,e15,e16};
            float y = 0.f;
            #pragma unroll
            for (int s = 0; s < 16; ++s) {
                h[s] = fmaf(pw[s], h[s], dtx * bp[s]);
                y = fmaf(h[s], cp[s], y);
            }
            float res = bf2f(xz[row * 1024 + 512 + d]);
            float g = (y + x * Dd) * (res / (1.f + __expf(-res)));
            xi[row * 512 + d] = f2bf(g);
        }
    } else {
        for (int t = t0; t < t0 + CLEN; ++t) {
            size_t row = (size_t)b * LL + t;
            float dt = bf2f(dtb[row * 512 + d]);
            float x = bf2f(xi[row * 512 + d]);
            float dtx = dt * x;
            const float* bp = bc + row * 32;
            const float* cp = bc + row * 32 + 16;
            float y = 0.f;
            #pragma unroll
            for (int s = 0; s < 16; ++s) {
                float dA = __expf(dt * Av[s]);
                h[s] = fmaf(dA, h[s], dtx * bp[s]);
                y = fmaf(h[s], cp[s], y);
            }
            float res = bf2f(xz[row * 1024 + 512 + d]);
            float g = (y + x * Dd) * (res / (1.f + __expf(-res)));
            xi[row * 512 + d] = f2bf(g);
        }
    }
}

// ---------------- fused tail: out_proj(last row) + residual + LN + head ----
__global__ __launch_bounds__(256) void tail_kernel(
    const ushort* __restrict__ xi, const float* __restrict__ W,
    const ushort* __restrict__ hbf,
    const float* __restrict__ lng, const float* __restrict__ lnb,
    const float* __restrict__ hw, const float* __restrict__ hb,
    float* __restrict__ out)
{
    int b = blockIdx.x, tid = threadIdx.x;
    __shared__ float sy[DI];
    __shared__ float sh[DM];
    __shared__ float r1[4], r2[4];
    const ushort* yrow = xi + ((size_t)b * LL + (LL - 1)) * DI;
    for (int k = tid; k < DI; k += 256) sy[k] = bf2f(yrow[k]);
    __syncthreads();
    const float* wr = W + (size_t)tid * DI;
    float acc = 0.f;
    for (int k = 0; k < DI; k += 4) {
        float4 wv = *(const float4*)(wr + k);
        acc = fmaf(sy[k+0], wv.x, acc);
        acc = fmaf(sy[k+1], wv.y, acc);
        acc = fmaf(sy[k+2], wv.z, acc);
        acc = fmaf(sy[k+3], wv.w, acc);
    }
    float v = acc + bf2f(hbf[((size_t)b * LL + (LL - 1)) * DM + tid]);

    float s = v;
    #pragma unroll
    for (int o = 32; o >= 1; o >>= 1) s += __shfl_down(s, o);
    if ((tid & 63) == 0) r1[tid >> 6] = s;
    __syncthreads();
    float mu = (r1[0] + r1[1] + r1[2] + r1[3]) * (1.f / 256.f);
    float dv = v - mu;
    float q = dv * dv;
    #pragma unroll
    for (int o = 32; o >= 1; o >>= 1) q += __shfl_down(q, o);
    if ((tid & 63) == 0) r2[tid >> 6] = q;
    __syncthreads();
    float var = (r2[0] + r2[1] + r2[2] + r2[3]) * (1.f / 256.f);
    sh[tid] = dv * rsqrtf(var + LN_EPS) * lng[tid] + lnb[tid];
    __syncthreads();
    if (tid < NOUTK) {
        const float* hr = hw + (size_t)tid * DM;
        float a2 = hb[tid];
        for (int d2 = 0; d2 < DM; d2 += 4) {
            float4 wv = *(const float4*)(hr + d2);
            a2 = fmaf(sh[d2+0], wv.x, a2);
            a2 = fmaf(sh[d2+1], wv.y, a2);
            a2 = fmaf(sh[d2+2], wv.z, a2);
            a2 = fmaf(sh[d2+3], wv.w, a2);
        }
        out[b * NOUTK + tid] = a2;
    }
}

extern "C" void kernel_launch(void* const* d_in, const int* in_sizes, int n_in,
                              void* d_out, int out_size, void* d_ws, size_t ws_size,
                              hipStream_t stream)
{
    const float* x    = (const float*)d_in[0];
    const float* encw = (const float*)d_in[1];
    const float* encb = (const float*)d_in[2];
    const float* inw  = (const float*)d_in[3];
    const float* cw   = (const float*)d_in[4];
    const float* cb   = (const float*)d_in[5];
    const float* xpw  = (const float*)d_in[6];
    const float* dtw  = (const float*)d_in[7];
    const float* dtb  = (const float*)d_in[8];
    const float* alog = (const float*)d_in[9];
    const float* Dp   = (const float*)d_in[10];
    const float* opw  = (const float*)d_in[11];
    const float* lng  = (const float*)d_in[12];
    const float* lnb  = (const float*)d_in[13];
    const float* hw   = (const float*)d_in[14];
    const float* hb   = (const float*)d_in[15];
    float* out = (float*)d_out;

    float* ws   = (float*)d_ws;
    float* bc   = ws;                               // BL*32 f32 (B|C)
    float* cS   = bc  + (size_t)BL * 32;            // B*DI*NC f32 (sum dt)
    float* cH   = cS  + (size_t)BB * DI * NC;       // B*DI*NC*16 f32
    ushort* h_bf    = (ushort*)(cH + (size_t)BB * DI * NC * DS);  // BL*256
    ushort* xz_bf   = h_bf  + (size_t)BL * DM;      // BL*1024
    ushort* xi_bf   = xz_bf + (size_t)BL * 1024;    // BL*512
    ushort* dt_bf   = xi_bf + (size_t)BL * DI;      // BL*512 (softplus'd dt)
    ushort* inw_bf  = dt_bf + (size_t)BL * DI;      // 2*1024*256
    ushort* opw_bf  = inw_bf + 2 * 1024 * DM;       // 2*256*512
    ushort* comb_bf = opw_bf + 2 * DM * DI;         // 2*640*512

    dim3 blk(256, 1, 1);

    prep_enc_kernel<<<dim3(PREP_BLOCKS + ENC_BLOCKS), blk, 0, stream>>>(
        inw, opw, xpw, dtw, inw_bf, opw_bf, comb_bf,
        x, encw, encb, h_bf);

    for (int l = 0; l < 2; ++l) {
        // in_proj -> xz_bf (bf16 only)
        mfma_gemm<0><<<dim3(1024/128, BL/64), blk, 0, stream>>>(
            h_bf, DM, inw_bf + (size_t)l * 1024 * DM, nullptr,
            nullptr, 0, xz_bf, 1024, DM);
        // conv + silu -> xi_bf
        conv_silu_kernel<<<dim3(BL * 64 / 8 / 256), blk, 0, stream>>>(
            xz_bf, cw + l * DI * 4, cb + l * DI, xi_bf);
        // combined xproj+dtproj: dt_bf = bf16(softplus(xi@Wdt^T + dtb)),
        // bc = f32 [B|C]
        mfma_gemm<1><<<dim3(LDB/128, BL/64), blk, 0, stream>>>(
            xi_bf, DI, comb_bf + (size_t)l * LDB * DI, dtb + l * DI,
            bc, 32, dt_bf, 512, DI);
        // scan
        scan_phase1<<<dim3(NC, BB, 2), blk, 0, stream>>>(
            xi_bf, dt_bf, bc, alog + (size_t)l * DI * 16, cS, cH);
        scan_phase2<<<dim3(BB * DI), blk, 0, stream>>>(
            cS, cH, alog + (size_t)l * DI * 16);
        if (l == 0) {
            scan_phase3<<<dim3(NC, BB, 2), blk, 0, stream>>>(
                xz_bf, xi_bf, dt_bf, bc, alog + (size_t)l * DI * 16,
                Dp + l * DI, cH, 0);
            // out_proj with bf16 residual read-modify-write on h_bf
            mfma_gemm<2><<<dim3(DM/128, BL/64), blk, 0, stream>>>(
                xi_bf, DI, opw_bf + (size_t)l * DM * DI, nullptr,
                nullptr, 0, h_bf, DM, DI);
        } else {
            scan_phase3<<<dim3(1, BB, 2), blk, 0, stream>>>(
                xz_bf, xi_bf, dt_bf, bc, alog + (size_t)l * DI * 16,
                Dp + l * DI, cH, NC - 1);
            tail_kernel<<<dim3(BB), blk, 0, stream>>>(
                xi_bf, opw + (size_t)l * DM * DI, h_bf,
                lng, lnb, hw, hb, out);
        }
    }
}